// Round 6
// baseline (346.731 us; speedup 1.0000x reference)
//
#include <hip/hip_runtime.h>
#include <math.h>

#define HOP     200
#define NB      32
#define TLEN    480000
#define NSEGT   2400                   // 200-sample segments per batch row
#define WSEG    10                     // output segments per WAVE
#define WPS     (WSEG + 6)             // 16 partial segments per wave
#define NWT     (NSEGT / WSEG)         // 240 wave-tiles per batch row
#define WPB     4                      // waves per 256-thread block
#define NBLKX   (NWT / WPB)            // 60 blocks in x

#define DLT  0.00785398163397448f      // 2*pi/800
#define C1K  0.99996915760f
#define S1K  0.00785390090f
#define C2K  0.99987663248f
#define S2K  0.01570731731f
#define C3K  0.99972243010f
#define S3K  0.02355976470f
#define C40  0.95105651629515f
#define S40  0.30901699437495f

typedef float floatx4 __attribute__((ext_vector_type(4)));

#define WSYNC() asm volatile("s_waitcnt lgkmcnt(0)" ::: "memory")

// ===========================================================================
// ABLATION PROBES (R6 measurement round). Each probe repeats its work REP
// times (opaque asm breaks cross-rep CSE/hoisting, rule #17) to exceed the
// ~43us rocprof top-5 visibility cutoff. All probe output is overwritten by
// the real kernel, which launches LAST.
// ===========================================================================

// Probe 1: pure stream copy, nontemporal stores (our kernel's store type).
__global__ __launch_bounds__(256) void abl_copy(const float* x, float* out) {
    const int b = blockIdx.y;
    const float4* xg = (const float4*)(x + (size_t)b * TLEN) + 2000 * blockIdx.x;
    floatx4* og = (floatx4*)(out + (size_t)b * TLEN) + 2000 * blockIdx.x;
    for (int rep = 0; rep < 4; ++rep) {
        for (int j = threadIdx.x; j < 2000; j += 256) {
            float4 v = xg[j];
            asm volatile("" : "+v"(v.x), "+v"(v.y), "+v"(v.z), "+v"(v.w));
            floatx4 rv = {v.x, v.y, v.z, v.w};
            __builtin_nontemporal_store(rv, &og[j]);
        }
    }
}

// Probe 2: pure stream copy, PLAIN stores (isolates NT-store pathology).
__global__ __launch_bounds__(256) void abl_copy_nc(const float* x, float* out) {
    const int b = blockIdx.y;
    const float4* xg = (const float4*)(x + (size_t)b * TLEN) + 2000 * blockIdx.x;
    floatx4* og = (floatx4*)(out + (size_t)b * TLEN) + 2000 * blockIdx.x;
    for (int rep = 0; rep < 4; ++rep) {
        for (int j = threadIdx.x; j < 2000; j += 256) {
            float4 v = xg[j];
            asm volatile("" : "+v"(v.x), "+v"(v.y), "+v"(v.z), "+v"(v.w));
            floatx4 rv = {v.x, v.y, v.z, v.w};
            og[j] = rv;
        }
    }
}

// Probe 3: exact Phase A+B (read + trig + LDS partials + fold), sink->out.
// x arg NOT __restrict__: sink stores force x reloads each rep.
__global__ __launch_bounds__(256) void abl_pA(const float* x, float* sink) {
    __shared__ float part[WPB][WPS][10][6];
    const int w    = threadIdx.x >> 6;
    const int lane = threadIdx.x & 63;
    const int b    = blockIdx.y;
    const int wt   = blockIdx.x * WPB + w;
    const int wq0  = wt * WSEG;
    const float* xb = x + (size_t)b * TLEN;

    for (int rep = 0; rep < 3; ++rep) {
        int ro = 0; asm volatile("" : "+v"(ro));     // 0, opaque per rep
        for (int u = lane; u < WPS * 10; u += 64) {
            const int s = u / 10;
            const int k = u - 10 * s;
            const int g = wq0 - 3 + s;
            const int gm = (g + 4) & 3;
            float c0, sn0;
            __sincosf((float)(gm * 200 + 4 * k + ro) * DLT, &sn0, &c0);

            float4 v[5];
            if (g >= 0 && g <= 2399) {
                const float4* xs = (const float4*)(xb + 200 * g);
#pragma unroll
                for (int i = 0; i < 5; ++i) v[i] = xs[k + 10 * i];
            } else {
                const float e = (g < 0) ? xb[0] : xb[TLEN - 1];
#pragma unroll
                for (int i = 0; i < 5; ++i) v[i] = make_float4(e, e, e, e);
            }

            float p1e = 0.f, p1o = 0.f, pce = 0.f, pco = 0.f, pse = 0.f, pso = 0.f;
#pragma unroll
            for (int i = 0; i < 5; ++i) {
                const float c1 = c0 * C1K - sn0 * S1K, s1 = sn0 * C1K + c0 * S1K;
                const float c2 = c0 * C2K - sn0 * S2K, s2 = sn0 * C2K + c0 * S2K;
                const float c3 = c0 * C3K - sn0 * S3K, s3 = sn0 * C3K + c0 * S3K;
                p1e += v[i].x + v[i].z;             p1o += v[i].y + v[i].w;
                pce += c0 * v[i].x + c2 * v[i].z;   pco += c1 * v[i].y + c3 * v[i].w;
                pse += sn0 * v[i].x + s2 * v[i].z;  pso += s1 * v[i].y + s3 * v[i].w;
                const float cn = c0 * C40 - sn0 * S40;
                sn0 = sn0 * C40 + c0 * S40;  c0 = cn;
            }
            part[w][s][k][0] = p1e;  part[w][s][k][1] = p1o;
            part[w][s][k][2] = pce;  part[w][s][k][3] = pco;
            part[w][s][k][4] = pse;  part[w][s][k][5] = pso;
        }
        WSYNC();
        for (int u = lane; u < WPS * 6; u += 64) {
            const int s = u / 6;
            const int c = u - 6 * s;
            float a = 0.f;
#pragma unroll
            for (int k = 0; k < 10; ++k) a += part[w][s][k][c];
            sink[(((size_t)b * NWT + wt) * WPS + s) * 6 + c] = a;
        }
        WSYNC();
    }
}

// Probe 4: exact Phase D (read + 4x cos + NT write), fabricated finite segc.
__global__ __launch_bounds__(256) void abl_pD(const float* x, float* out) {
    __shared__ float4 segc[WPB][2][WSEG];
    const int w    = threadIdx.x >> 6;
    const int lane = threadIdx.x & 63;
    const int b    = blockIdx.y;
    const int wt   = blockIdx.x * WPB + w;
    const int wq0  = wt * WSEG;
    const float* xb = x + (size_t)b * TLEN;

    if (lane < 2 * WSEG) {
        const int par = lane & 1;
        const int ql  = lane >> 1;
        float sA, cA;
        __sincosf((float)(wq0 + ql + par) * 0.01f, &sA, &cA);
        segc[w][par][ql] = make_float4(cA * 0.1f, sA * 0.1f + 0.2f, cA, 0.f);
    }
    WSYNC();

    const float4* xg4 = (const float4*)xb + 50 * wq0;
    floatx4* og4 = (floatx4*)(out + (size_t)b * TLEN) + 50 * wq0;
    const int pmb = (wq0 & 3) * 200 + 400;
    for (int rep = 0; rep < 3; ++rep) {
        int ro = 0; asm volatile("" : "+v"(ro));     // 0, opaque per rep
        for (int j = lane; j < 50 * WSEG; j += 64) {
            const float4 xv = xg4[j];
            const int sl = j / 50;
            const float4 ce = segc[w][0][sl];
            const float4 co = segc[w][1][sl];
            const int pm = (pmb + 4 * j + ro) % 800;
            const float xa[4] = {xv.x, xv.y, xv.z, xv.w};
            float r[4];
#pragma unroll
            for (int c = 0; c < 4; ++c) {
                const float4 cc = (c & 1) ? co : ce;
                r[c] = 0.75f * xa[c] + cc.x - cc.y * __cosf((float)(pm + c) * DLT - cc.z);
            }
            floatx4 rv = {r[0], r[1], r[2], r[3]};
            __builtin_nontemporal_store(rv, &og4[j]);
        }
    }
}

// ===========================================================================
// REAL kernel — R5 wave-autonomous build, verbatim (41.7us, passes).
// Launches LAST so every output element is correct.
// ===========================================================================
__global__ __launch_bounds__(256) void stft_wave(const float* __restrict__ x,
                                                 float* __restrict__ out) {
    __shared__ float  part[WPB][WPS][10][6];
    __shared__ float  pg[WPB][WPS][6];
    __shared__ float4 segc[WPB][2][WSEG];

    const int w    = threadIdx.x >> 6;
    const int lane = threadIdx.x & 63;
    const int b    = blockIdx.y;
    const int wt   = blockIdx.x * WPB + w;
    const int wq0  = wt * WSEG;
    const float* xb = x + (size_t)b * TLEN;

    for (int u = lane; u < WPS * 10; u += 64) {
        const int s = u / 10;
        const int k = u - 10 * s;
        const int g = wq0 - 3 + s;
        const int gm = (g + 4) & 3;
        float c0, sn0;
        __sincosf((float)(gm * 200 + 4 * k) * DLT, &sn0, &c0);

        float4 v[5];
        if (g >= 0 && g <= 2399) {
            const float4* xs = (const float4*)(xb + 200 * g);
#pragma unroll
            for (int i = 0; i < 5; ++i) v[i] = xs[k + 10 * i];
        } else {
            const float e = (g < 0) ? xb[0] : xb[TLEN - 1];
#pragma unroll
            for (int i = 0; i < 5; ++i) v[i] = make_float4(e, e, e, e);
        }

        float p1e = 0.f, p1o = 0.f, pce = 0.f, pco = 0.f, pse = 0.f, pso = 0.f;
#pragma unroll
        for (int i = 0; i < 5; ++i) {
            const float c1 = c0 * C1K - sn0 * S1K, s1 = sn0 * C1K + c0 * S1K;
            const float c2 = c0 * C2K - sn0 * S2K, s2 = sn0 * C2K + c0 * S2K;
            const float c3 = c0 * C3K - sn0 * S3K, s3 = sn0 * C3K + c0 * S3K;
            p1e += v[i].x + v[i].z;             p1o += v[i].y + v[i].w;
            pce += c0 * v[i].x + c2 * v[i].z;   pco += c1 * v[i].y + c3 * v[i].w;
            pse += sn0 * v[i].x + s2 * v[i].z;  pso += s1 * v[i].y + s3 * v[i].w;
            const float cn = c0 * C40 - sn0 * S40;
            sn0 = sn0 * C40 + c0 * S40;  c0 = cn;
        }
        part[w][s][k][0] = p1e;  part[w][s][k][1] = p1o;
        part[w][s][k][2] = pce;  part[w][s][k][3] = pco;
        part[w][s][k][4] = pse;  part[w][s][k][5] = pso;
    }
    WSYNC();

    for (int u = lane; u < WPS * 6; u += 64) {
        const int s = u / 6;
        const int c = u - 6 * s;
        float a = 0.f;
#pragma unroll
        for (int k = 0; k < 10; ++k) a += part[w][s][k][c];
        pg[w][s][c] = a;
    }
    WSYNC();

    if (lane < 2 * WSEG) {
        const int par = lane & 1;
        const int ql  = lane >> 1;
        const int q   = wq0 + ql;
        float A = 0.f, C = 0.f, D = 0.f;
#pragma unroll
        for (int df = -1; df <= 2; ++df) {
            const int f = q + df;
            if (f < 0 || f > 2400) continue;
            const int ls0 = f - wq0 + 1;
            float sp1 = 0.f, spc = 0.f, sps = 0.f;
#pragma unroll
            for (int kk = 0; kk < 4; ++kk) {
                const float* rec = pg[w][ls0 + kk];
                sp1 += rec[par];  spc += rec[2 + par];  sps += rec[4 + par];
            }
            const int fm = f & 3;
            const float tr = (fm == 0) ? spc : (fm == 1) ? sps : (fm == 2) ? -spc : -sps;
            const float S = 0.5f * sp1 + 0.5f * tr;
            A += S;
            if (fm == 0) C += S; else if (fm == 2) C -= S;
            else if (fm == 1) D += S; else D -= S;
        }
        segc[w][par][ql] = make_float4(A * (1.0f / 1600.0f),
                                       sqrtf(C * C + D * D) * (1.0f / 1600.0f),
                                       atan2f(D, C), 0.f);
    }
    WSYNC();

    const bool headw = (wq0 == 0);
    const bool tailw = (wq0 + WSEG == NSEGT);
    const float4* xg4 = (const float4*)xb + 50 * wq0;
    floatx4* og4 = (floatx4*)(out + (size_t)b * TLEN) + 50 * wq0;
    const int pmb = (wq0 & 3) * 200 + 400;
    for (int j = lane; j < 50 * WSEG; j += 64) {
        const float4 xv = xg4[j];
        const int sl = j / 50;
        const float4 ce = segc[w][0][sl];
        const float4 co = segc[w][1][sl];
        const int pm = (pmb + 4 * j) % 800;
        const float xa[4] = {xv.x, xv.y, xv.z, xv.w};
        float r[4];
#pragma unroll
        for (int c = 0; c < 4; ++c) {
            const float4 cc = (c & 1) ? co : ce;
            r[c] = 0.75f * xa[c] + cc.x - cc.y * __cosf((float)(pm + c) * DLT - cc.z);
        }
        if (headw && sl == 0) {
#pragma unroll
            for (int c = 0; c < 4; ++c) {
                const float wm = 0.5f + 0.5f * __sinf((float)(pm + c) * DLT);
                r[c] -= 0.5f * wm * wm * xa[c];
            }
        }
        if (tailw && sl == WSEG - 1) {
#pragma unroll
            for (int c = 0; c < 4; ++c) {
                const float wm = 0.5f - 0.5f * __sinf((float)(pm + c) * DLT);
                r[c] -= 0.5f * wm * wm * xa[c];
            }
        }
        floatx4 rv = {r[0], r[1], r[2], r[3]};
        __builtin_nontemporal_store(rv, &og4[j]);
    }
}

extern "C" void kernel_launch(void* const* d_in, const int* in_sizes, int n_in,
                              void* d_out, int out_size, void* d_ws, size_t ws_size,
                              hipStream_t stream) {
    const float* x = (const float*)d_in[0];
    float* out = (float*)d_out;
    // Ablation probes (output garbage, fully overwritten by stft_wave below).
    abl_copy   <<<dim3(NBLKX, NB), dim3(256), 0, stream>>>(x, out);
    abl_copy_nc<<<dim3(NBLKX, NB), dim3(256), 0, stream>>>(x, out);
    abl_pA     <<<dim3(NBLKX, NB), dim3(256), 0, stream>>>(x, out);
    abl_pD     <<<dim3(NBLKX, NB), dim3(256), 0, stream>>>(x, out);
    // Real kernel LAST -> correct output.
    stft_wave  <<<dim3(NBLKX, NB), dim3(256), 0, stream>>>(x, out);
}

// Round 7
// 132.045 us; speedup vs baseline: 2.6259x; 2.6259x over previous
//
#include <hip/hip_runtime.h>
#include <math.h>

#define HOP     200
#define NB      32
#define TLEN    480000
#define NSEGT   2400                   // 200-sample segments per batch row
#define WSEG    10                     // output segments per wave-tile
#define WPS     (WSEG + 6)             // 16 partial segments per tile
#define NTPW    3                      // tiles per persistent wave
#define WPB     2                      // waves per block (128 threads)
#define PWR     (NSEGT / (WSEG * NTPW))  // 80 persistent waves per batch row
#define NBLKX   (PWR / WPB)            // 40 blocks in x

#define DLT  0.00785398163397448f      // 2*pi/800
// cos/sin of k*DLT, k=1..3 (within-float4 angle stepping)
#define C1K  0.99996915760f
#define S1K  0.00785390090f
#define C2K  0.99987663248f
#define S2K  0.01570731731f
#define C3K  0.99972243010f
#define S3K  0.02355976470f
// rotation by 40*DLT = pi/10 (between a thread's successive float4s)
#define C40  0.95105651629515f
#define S40  0.30901699437495f

typedef float floatx4 __attribute__((ext_vector_type(4)));

// Wave-local phase separator (no s_barrier): all cross-lane traffic stays
// inside one wave's private LDS slice; lanes are lockstep and the DS unit
// is in-order per wave, so an lgkm drain suffices.
#define WSYNC() asm volatile("s_waitcnt lgkmcnt(0)" ::: "memory")

// Analytic collapse (validated in prior session):
//   out[p] = 0.75*x[t] + A'(q,par) - R'(q,par)*cos(p*DLT - psi)  [+ edge w^2 corr]
//
// R7 structure: persistent wave-autonomous tiles with FUSED D(t)||A(t+1).
// R6's ablation measured the traffic floor: a pure read+NT-write copy of
// exactly our I/O runs at ~19-21us (abl_copy, 6.4 TB/s app-level) BECAUSE
// reads and writes interleave at instruction granularity in every wave.
// All prior builds (41.5us plateau) separated bulk-read Phase A from
// bulk-write Phase D; with the whole grid resident from t=0 these phases
// stay chip-wide correlated (no barriers needed for lockstep - identical
// code + identical start). Here each wave owns NTPW=3 consecutive tiles and
// runs ONE loop interleaving D(t)'s load/compute/store with A(t+1)'s
// loads/accumulate: every wave reads AND writes all the time, like abl_copy.
// 1280 blocks of 128 thr = exactly 5 blocks/CU, balanced; 10 waves/CU.
// Math identical -> bit-identical output.
__global__ __launch_bounds__(128) void stft_pipe(const float* __restrict__ x,
                                                 float* __restrict__ out) {
    __shared__ float  part[WPB][WPS][10][6];   // 7.7 KB
    __shared__ float  pg[WPB][WPS][6];         // 0.8 KB
    __shared__ float4 segc[WPB][2][WSEG];      // 0.6 KB

    const int w     = threadIdx.x >> 6;        // wave id within block
    const int lane  = threadIdx.x & 63;
    const int b     = blockIdx.y;
    const int pw    = blockIdx.x * WPB + w;    // persistent-wave id
    const int tbase = pw * NTPW;               // first tile of this wave
    const float* xb = x + (size_t)b * TLEN;
    float* ob       = out + (size_t)b * TLEN;

    // ---- Phase A item: basis partials for one (segment,k) of tile q0 ----
    auto A_item = [&](int q0, int u) {
        const int s = u / 10;
        const int k = u - 10 * s;
        const int g = q0 - 3 + s;               // may be OOB (edge pad)
        const int gm = (g + 4) & 3;             // t mod 800 phase
        float c0, sn0;
        __sincosf((float)(gm * 200 + 4 * k) * DLT, &sn0, &c0);

        float4 v[5];
        if (g >= 0 && g <= 2399) {
            const float4* xs = (const float4*)(xb + 200 * g);
#pragma unroll
            for (int i = 0; i < 5; ++i) v[i] = xs[k + 10 * i];
        } else {
            const float e = (g < 0) ? xb[0] : xb[TLEN - 1];
#pragma unroll
            for (int i = 0; i < 5; ++i) v[i] = make_float4(e, e, e, e);
        }

        float p1e = 0.f, p1o = 0.f, pce = 0.f, pco = 0.f, pse = 0.f, pso = 0.f;
#pragma unroll
        for (int i = 0; i < 5; ++i) {
            const float c1 = c0 * C1K - sn0 * S1K, s1 = sn0 * C1K + c0 * S1K;
            const float c2 = c0 * C2K - sn0 * S2K, s2 = sn0 * C2K + c0 * S2K;
            const float c3 = c0 * C3K - sn0 * S3K, s3 = sn0 * C3K + c0 * S3K;
            p1e += v[i].x + v[i].z;             p1o += v[i].y + v[i].w;
            pce += c0 * v[i].x + c2 * v[i].z;   pco += c1 * v[i].y + c3 * v[i].w;
            pse += sn0 * v[i].x + s2 * v[i].z;  pso += s1 * v[i].y + s3 * v[i].w;
            const float cn = c0 * C40 - sn0 * S40;   // advance 40 samples
            sn0 = sn0 * C40 + c0 * S40;  c0 = cn;
        }
        part[w][s][k][0] = p1e;  part[w][s][k][1] = p1o;
        part[w][s][k][2] = pce;  part[w][s][k][3] = pco;
        part[w][s][k][4] = pse;  part[w][s][k][5] = pso;
    };

    // ---- Phase B: fold 10 sub-partials per segment ----
    auto phaseB = [&]() {
        for (int u = lane; u < WPS * 6; u += 64) {
            const int s = u / 6;
            const int c = u - 6 * s;
            float a = 0.f;
#pragma unroll
            for (int k = 0; k < 10; ++k) a += part[w][s][k][c];
            pg[w][s][c] = a;
        }
    };

    // ---- Phase C: per-(segment,parity) trig constants, masked frames ----
    auto phaseC = [&](int q0) {
        if (lane < 2 * WSEG) {
            const int par = lane & 1;
            const int ql  = lane >> 1;
            const int q   = q0 + ql;
            float A = 0.f, C = 0.f, D = 0.f;
#pragma unroll
            for (int df = -1; df <= 2; ++df) {
                const int f = q + df;
                if (f < 0 || f > 2400) continue;     // boundary frame mask
                const int ls0 = f - q0 + 1;          // local pg row of g=f-2
                float sp1 = 0.f, spc = 0.f, sps = 0.f;
#pragma unroll
                for (int kk = 0; kk < 4; ++kk) {
                    const float* rec = pg[w][ls0 + kk];
                    sp1 += rec[par];  spc += rec[2 + par];  sps += rec[4 + par];
                }
                const int fm = f & 3;
                const float tr = (fm == 0) ? spc : (fm == 1) ? sps : (fm == 2) ? -spc : -sps;
                const float S = 0.5f * sp1 + 0.5f * tr;
                A += S;
                if (fm == 0) C += S; else if (fm == 2) C -= S;
                else if (fm == 1) D += S; else D -= S;
            }
            segc[w][par][ql] = make_float4(A * (1.0f / 1600.0f),
                                           sqrtf(C * C + D * D) * (1.0f / 1600.0f),
                                           atan2f(D, C), 0.f);
        }
    };

    // ---- Phase D compute+store for one float4 (load supplied by caller) ----
    auto D_comp = [&](int q0, int j, const float4& xv, bool headw, bool tailw) {
        const int sl = j / 50;
        const float4 ce = segc[w][0][sl];
        const float4 co = segc[w][1][sl];
        const int pm = (((q0 & 3) * 200 + 400) + 4 * j) % 800;
        const float xa[4] = {xv.x, xv.y, xv.z, xv.w};
        float r[4];
#pragma unroll
        for (int c = 0; c < 4; ++c) {
            const float4 cc = (c & 1) ? co : ce;
            r[c] = 0.75f * xa[c] + cc.x - cc.y * __cosf((float)(pm + c) * DLT - cc.z);
        }
        if (headw && sl == 0) {           // missing frame's w^2 term (analytic)
#pragma unroll
            for (int c = 0; c < 4; ++c) {
                const float wm = 0.5f + 0.5f * __sinf((float)(pm + c) * DLT);
                r[c] -= 0.5f * wm * wm * xa[c];
            }
        }
        if (tailw && sl == WSEG - 1) {
#pragma unroll
            for (int c = 0; c < 4; ++c) {
                const float wm = 0.5f - 0.5f * __sinf((float)(pm + c) * DLT);
                r[c] -= 0.5f * wm * wm * xa[c];
            }
        }
        floatx4 rv = {r[0], r[1], r[2], r[3]};
        __builtin_nontemporal_store(rv, (floatx4*)ob + 50 * q0 + j);
    };

    // ---- prologue: A/B/C of first tile ----
    {
        const int q0 = tbase * WSEG;
        for (int u = lane; u < WPS * 10; u += 64) A_item(q0, u);
        WSYNC();
        phaseB();
        WSYNC();
        phaseC(q0);
        WSYNC();
    }

    // ---- main: fused D(t) || A(t+1), then B/C(t+1); last tile D plain ----
    for (int tt = 0; tt < NTPW; ++tt) {
        const int t  = tbase + tt;
        const int q0 = t * WSEG;
        const bool headw = (q0 == 0);
        const bool tailw = (q0 + WSEG == NSEGT);

        if (tt + 1 < NTPW) {
            const int q2 = q0 + WSEG;           // next tile
#pragma unroll
            for (int kk = 0; kk < 8; ++kk) {
                const int j = lane + 64 * kk;
                const bool dj = (j < 50 * WSEG);
                float4 xv;
                if (dj) xv = ((const float4*)xb)[50 * q0 + j];   // D load first
                if ((kk & 1) == 0 && kk < 6) {                   // kk=0,2,4
                    const int u = lane + 64 * (kk >> 1);
                    if (u < WPS * 10) A_item(q2, u);             // A(t+1) item
                }
                if (dj) D_comp(q0, j, xv, headw, tailw);         // D compute+NT store
            }
            WSYNC();
            phaseB();
            WSYNC();
            phaseC(q2);
            WSYNC();
        } else {
            for (int j = lane; j < 50 * WSEG; j += 64) {
                const float4 xv = ((const float4*)xb)[50 * q0 + j];
                D_comp(q0, j, xv, headw, tailw);
            }
        }
    }
}

extern "C" void kernel_launch(void* const* d_in, const int* in_sizes, int n_in,
                              void* d_out, int out_size, void* d_ws, size_t ws_size,
                              hipStream_t stream) {
    const float* x = (const float*)d_in[0];
    float* out = (float*)d_out;
    stft_pipe<<<dim3(NBLKX, NB), dim3(128), 0, stream>>>(x, out);
}

// Round 8
// 124.665 us; speedup vs baseline: 2.7813x; 1.0592x over previous
//
#include <hip/hip_runtime.h>
#include <math.h>

#define HOP     200
#define NB      32
#define TLEN    480000
#define NSEGT   2400                   // 200-sample segments per batch row
#define WSEG    10                     // output segments per tile
#define NWT     (NSEGT / WSEG)         // 240 tiles per batch row
#define NTPB    6                      // tiles per block (pipeline length)
#define NBLKX   (NWT / NTPB)           // 40 blocks in x  -> 1280 blocks = 5/CU
#define RING    32                     // pg ring rows (live span is 26)

#define DLT  0.00785398163397448f      // 2*pi/800
// cos/sin of k*DLT, k=1..3 (within-float4 angle stepping)
#define C1K  0.99996915760f
#define S1K  0.00785390090f
#define C2K  0.99987663248f
#define S2K  0.01570731731f
#define C3K  0.99972243010f
#define S3K  0.02355976470f
// rotation by 40*DLT = pi/10 (between a producer thread's successive float4s)
#define C40  0.95105651629515f
#define S40  0.30901699437495f
// rotation by 512*DLT = 1.28*pi (consumer lane's m-step, 128-lane stride * 4)
#define C512 -0.63742398974869f
#define S512 -0.77051324277579f

typedef float floatx4 __attribute__((ext_vector_type(4)));

// In-wave LDS ordering (producer A->B on wave-private rows).
#define WSYNC() asm volatile("s_waitcnt lgkmcnt(0)" ::: "memory")
// Stage barrier: LDS drain + barrier. No vmcnt drain (nothing global is
// cross-wave; NT stores / x loads legitimately stay in flight).
#define LBAR()  asm volatile("s_waitcnt lgkmcnt(0)\n\ts_barrier" ::: "memory")

// R8: producer/consumer wave specialization.
// Evidence: phases A and D each cost ~21-23us (R6 ablation arithmetic) and
// serialize in every homogeneous-wave build (R0-R7 all ~41.5us; conserved
// under data-source changes R2/R3, barrier removal R5, intra-wave fusion R7).
// Here waves 0-1 produce basis partials (Phase A+B) into a 32-row pg ring
// while waves 2-3 consume (Phase C for tile t+1, Phase D for tile t) -> A
// and D run CONCURRENTLY on different waves; steady state = max(A,D).
// Extra work cuts: ring kills the A halo (1.6x -> 1.067x); Phase C stores
// (A',C',D')/1600 directly (no sqrt/atan2); Phase D uses
//   R*cos(phi-psi) == C'*cos(phi) + D'*sin(phi)
// with a per-lane cos/sin rotation recurrence -> no trig, no int-mod in D;
// head/tail w^2 terms reuse the recurrence's sin(phi). Deltas O(1e-6).
__global__ __launch_bounds__(256) void stft_pc(const float* __restrict__ x,
                                               float* __restrict__ out) {
    __shared__ float  part[2][8][10][6];     // 3.8 KB producer-wave-private
    __shared__ float  pg[RING][6];           // 0.8 KB ring of segment partials
    __shared__ float4 segc[2][2][WSEG];      // 0.6 KB double-buffered [buf][par][seg]

    const int w    = threadIdx.x >> 6;       // 0,1 producers; 2,3 consumers
    const int lane = threadIdx.x & 63;
    const int b    = blockIdx.y;
    const int bt0  = blockIdx.x * NTPB;      // first global tile of this block
    const float* xb = x + (size_t)b * TLEN;
    float* ob       = out + (size_t)b * TLEN;

    // ---- producer: Phase A+B for rows [g0, g0+2*nrh), wave w owns nrh rows ----
    auto produce = [&](int g0, int nrh) {
        const int nb_ = w * nrh;
        for (int u = lane; u < nrh * 10; u += 64) {
            const int nl = u / 10;
            const int k  = u - 10 * nl;
            const int g  = g0 + nb_ + nl;
            const int gm = (g + 4) & 3;
            float c0, sn0;
            __sincosf((float)(gm * 200 + 4 * k) * DLT, &sn0, &c0);

            float4 v[5];
            if (g >= 0 && g <= 2399) {
                const float4* xs = (const float4*)(xb + 200 * g);
#pragma unroll
                for (int i = 0; i < 5; ++i) v[i] = xs[k + 10 * i];
            } else {                          // edge-pad segment: constant x
                const float e = (g < 0) ? xb[0] : xb[TLEN - 1];
#pragma unroll
                for (int i = 0; i < 5; ++i) v[i] = make_float4(e, e, e, e);
            }

            float p1e = 0.f, p1o = 0.f, pce = 0.f, pco = 0.f, pse = 0.f, pso = 0.f;
#pragma unroll
            for (int i = 0; i < 5; ++i) {
                const float c1 = c0 * C1K - sn0 * S1K, s1 = sn0 * C1K + c0 * S1K;
                const float c2 = c0 * C2K - sn0 * S2K, s2 = sn0 * C2K + c0 * S2K;
                const float c3 = c0 * C3K - sn0 * S3K, s3 = sn0 * C3K + c0 * S3K;
                p1e += v[i].x + v[i].z;             p1o += v[i].y + v[i].w;
                pce += c0 * v[i].x + c2 * v[i].z;   pco += c1 * v[i].y + c3 * v[i].w;
                pse += sn0 * v[i].x + s2 * v[i].z;  pso += s1 * v[i].y + s3 * v[i].w;
                const float cn = c0 * C40 - sn0 * S40;   // advance 40 samples
                sn0 = sn0 * C40 + c0 * S40;  c0 = cn;
            }
            part[w][nl][k][0] = p1e;  part[w][nl][k][1] = p1o;
            part[w][nl][k][2] = pce;  part[w][nl][k][3] = pco;
            part[w][nl][k][4] = pse;  part[w][nl][k][5] = pso;
        }
        WSYNC();                              // wave-private part visibility
        for (int u = lane; u < nrh * 6; u += 64) {
            const int nl = u / 6;
            const int c  = u - 6 * nl;
            float a = 0.f;
#pragma unroll
            for (int k = 0; k < 10; ++k) a += part[w][nl][k][c];
            pg[(g0 + nb_ + nl + RING) & (RING - 1)][c] = a;
        }
    };

    // ---- consumer: Phase C for local tile tl (writes segc[tl&1]) ----
    auto phaseC = [&](int tl) {
        const int cid = threadIdx.x & 127;
        if (cid < 2 * WSEG) {
            const int q0  = (bt0 + tl) * WSEG;
            const int par = cid & 1;
            const int ql  = cid >> 1;
            const int q   = q0 + ql;
            float A = 0.f, C = 0.f, D = 0.f;
#pragma unroll
            for (int df = -1; df <= 2; ++df) {
                const int f = q + df;
                if (f < 0 || f > 2400) continue;        // boundary frame mask
                float sp1 = 0.f, spc = 0.f, sps = 0.f;
#pragma unroll
                for (int kk = 0; kk < 4; ++kk) {
                    const float* rec = pg[(f - 2 + kk + RING) & (RING - 1)];
                    sp1 += rec[par];  spc += rec[2 + par];  sps += rec[4 + par];
                }
                const int fm = f & 3;
                const float tr = (fm == 0) ? spc : (fm == 1) ? sps : (fm == 2) ? -spc : -sps;
                const float S = 0.5f * sp1 + 0.5f * tr;
                A += S;
                if (fm == 0) C += S; else if (fm == 2) C -= S;
                else if (fm == 1) D += S; else D -= S;
            }
            segc[tl & 1][par][ql] = make_float4(A * (1.0f / 1600.0f),
                                                C * (1.0f / 1600.0f),
                                                D * (1.0f / 1600.0f), 0.f);
        }
    };

    // ---- consumer: Phase D for local tile tl (reads segc[tl&1]) ----
    auto phaseD = [&](int tl) {
        const int cid = threadIdx.x & 127;
        const int tg  = bt0 + tl;
        const int q0  = tg * WSEG;
        const int buf = tl & 1;
        const bool headw = (tg == 0);
        const bool tailw = (tg == NWT - 1);
        const float4* xg4 = (const float4*)xb + 50 * q0;
        floatx4* og4 = (floatx4*)ob + 50 * q0;
        const int pmb = (q0 & 3) * 200 + 400;

        float cf, sf;                          // cos/sin(phi) at c=0 of this lane
        __sincosf((float)(pmb + 4 * cid) * DLT, &sf, &cf);
#pragma unroll
        for (int m = 0; m < 4; ++m) {
            const int j = cid + 128 * m;
            if (j < 50 * WSEG) {
                const float4 xv = xg4[j];
                const int sl = j / 50;
                const float4 e = segc[buf][0][sl];   // (A',C',D') even parity
                const float4 o = segc[buf][1][sl];   // (A',C',D') odd parity
                const float c1f = cf * C1K - sf * S1K, s1f = sf * C1K + cf * S1K;
                const float c2f = cf * C2K - sf * S2K, s2f = sf * C2K + cf * S2K;
                const float c3f = cf * C3K - sf * S3K, s3f = sf * C3K + cf * S3K;
                float r0 = 0.75f * xv.x + e.x - (e.y * cf  + e.z * sf);
                float r1 = 0.75f * xv.y + o.x - (o.y * c1f + o.z * s1f);
                float r2 = 0.75f * xv.z + e.x - (e.y * c2f + e.z * s2f);
                float r3 = 0.75f * xv.w + o.x - (o.y * c3f + o.z * s3f);
                if (headw && sl == 0) {        // missing frame's w^2 (sin = sf chain)
                    const float w0 = 0.5f + 0.5f * sf,  w1 = 0.5f + 0.5f * s1f;
                    const float w2 = 0.5f + 0.5f * s2f, w3 = 0.5f + 0.5f * s3f;
                    r0 -= 0.5f * w0 * w0 * xv.x;  r1 -= 0.5f * w1 * w1 * xv.y;
                    r2 -= 0.5f * w2 * w2 * xv.z;  r3 -= 0.5f * w3 * w3 * xv.w;
                }
                if (tailw && sl == WSEG - 1) {
                    const float w0 = 0.5f - 0.5f * sf,  w1 = 0.5f - 0.5f * s1f;
                    const float w2 = 0.5f - 0.5f * s2f, w3 = 0.5f - 0.5f * s3f;
                    r0 -= 0.5f * w0 * w0 * xv.x;  r1 -= 0.5f * w1 * w1 * xv.y;
                    r2 -= 0.5f * w2 * w2 * xv.z;  r3 -= 0.5f * w3 * w3 * xv.w;
                }
                floatx4 rv = {r0, r1, r2, r3};
                __builtin_nontemporal_store(rv, &og4[j]);
            }
            const float cn = cf * C512 - sf * S512;   // advance 512 samples
            sf = sf * C512 + cf * S512;  cf = cn;
        }
    };

    // ---- 8-stage pipeline: stage s produces rows(t=s+1), C(t=s), D(t=s-1) ----
    for (int s = -1; s <= NTPB; ++s) {
        if (w < 2) {
            const int tp = s + 1;
            if (tp == 0) {
                // prologue: full 16 rows [q(0)-3, q(0)+13), 8 per wave
                produce(bt0 * WSEG - 3, 8);
            } else if (tp < NTPB) {
                // steady: 10 new rows [q(tp)+3, q(tp)+13), 5 per wave
                produce((bt0 + tp) * WSEG + 3, 5);
            }
        } else {
            if (s >= 0 && s < NTPB) phaseC(s);
            if (s >= 1)             phaseD(s - 1);
        }
        LBAR();
    }
}

extern "C" void kernel_launch(void* const* d_in, const int* in_sizes, int n_in,
                              void* d_out, int out_size, void* d_ws, size_t ws_size,
                              hipStream_t stream) {
    const float* x = (const float*)d_in[0];
    float* out = (float*)d_out;
    stft_pc<<<dim3(NBLKX, NB), dim3(256), 0, stream>>>(x, out);
}